// Round 17
// baseline (124.774 us; speedup 1.0000x reference)
//
#include <hip/hip_runtime.h>
#include <hip/hip_bf16.h>
#include <stdint.h>

// Problem constants
#define BB 8192
#define DD 1024
#define EE 8
#define HH 512
#define OO 1024
#define NG 16   // groups = expert*2 + which (0=primary,1=secondary)

typedef __bf16 bf16_t;
typedef bf16_t bf16x8 __attribute__((ext_vector_type(8)));
typedef float f32x4 __attribute__((ext_vector_type(4)));
typedef uint32_t u32;

// Padded counter stride: 64B per counter -> no cache-line sharing
#define CSTRIDE 16

// ---------------- ws layout (bytes) ----------------
#define WS_CNT    1024                                    // u32[16] stride 16
#define WS_RIDX   4096                                    // int[16][8192]  (512KB)
#define WS_RGATE  (4096 + NG*BB*4)                        // f32[16][8192]  (512KB)
#define WS_XB     (2u<<20)                                // bf16[8192][1024]
#define WS_W1T    (WS_XB + (size_t)BB*DD*2)               // bf16[8][512][1024]
#define WS_W2T    (WS_W1T + (size_t)EE*HH*DD*2)           // bf16[8][1024][512]
#define WS_H      (WS_W2T + (size_t)EE*OO*HH*2)           // bf16[18432][512]
// total ~54.5 MB

// async global->LDS, 16B per lane, LDS dest = wave-uniform base + lane*16
#define GL16(gsrc, ldst)                                                       \
  __builtin_amdgcn_global_load_lds(                                            \
      (const __attribute__((address_space(1))) void*)(gsrc),                   \
      (__attribute__((address_space(3))) void*)(ldst), 16, 0, 0)

// ---------------------------------------------------------------------------
// Co-launched prep + gate.
// Blocks [0,512): gate — 16 waves, 1 row/wave; f64 logits only (xb emission
//   moved to prep role: shortens the gate's latency-critical chain).
// Blocks [512,1024): prep — 16 rows of x->xb streaming (1 row/wave, fixed
//   round-16 OOB) + 4 x 64x64 W-transpose tiles per block.
// ---------------------------------------------------------------------------
union __align__(16) PGSmem {
  struct {
    float gLds[EE * DD];            // 32KB, [e][d]
    float s_imp[EE];
    u32   s_hist[NG];
    u32   s_base[NG];
    int   s_lb[NG][32];
    float s_lg[NG][32];
  } g;
  bf16_t t[4][64][72];              // 36.9KB (+8 pad -> 144B row stride)
};

__global__ __launch_bounds__(1024, 8) void k_pg(const float* __restrict__ x,
                                                const float* __restrict__ gW,
                                                const float* __restrict__ gb,
                                                const float* __restrict__ W1,
                                                const float* __restrict__ W2,
                                                float* __restrict__ imp,
                                                u32* __restrict__ cnt,
                                                int* __restrict__ ridx,
                                                float* __restrict__ rgate,
                                                bf16_t* __restrict__ xb,
                                                bf16_t* __restrict__ W1T,
                                                bf16_t* __restrict__ W2T) {
  __shared__ PGSmem sm;
  int tid = threadIdx.x;
  int bid = blockIdx.x;

  if (bid < 512) {
    // ---------------- gate role ----------------
    int lane = tid & 63, w = tid >> 6;
    int b = (bid << 4) + w;
    const float* xrow = x + (size_t)b * DD;

    // issue first two x-loads BEFORE staging: latency hides under gW stage
    f32x4 xv[4];
    xv[0] = *(const f32x4*)(xrow + (0 << 8) + (lane << 2));
    xv[1] = *(const f32x4*)(xrow + (1 << 8) + (lane << 2));

    if (tid < EE) sm.g.s_imp[tid] = 0.f;
    if (tid < NG) sm.g.s_hist[tid] = 0u;
    {
      const f32x4* gp = (const f32x4*)(gW + (size_t)tid * EE);
      f32x4 g0 = gp[0], g1 = gp[1];
      sm.g.gLds[0 * DD + tid] = g0.x; sm.g.gLds[1 * DD + tid] = g0.y;
      sm.g.gLds[2 * DD + tid] = g0.z; sm.g.gLds[3 * DD + tid] = g0.w;
      sm.g.gLds[4 * DD + tid] = g1.x; sm.g.gLds[5 * DD + tid] = g1.y;
      sm.g.gLds[6 * DD + tid] = g1.z; sm.g.gLds[7 * DD + tid] = g1.w;
    }
    __syncthreads();

    xv[2] = *(const f32x4*)(xrow + (2 << 8) + (lane << 2));
    xv[3] = *(const f32x4*)(xrow + (3 << 8) + (lane << 2));

    double acc[EE];
    #pragma unroll
    for (int e = 0; e < EE; ++e) acc[e] = 0.0;

    #pragma unroll
    for (int q = 0; q < 4; ++q) {
      int d0 = (q << 8) + (lane << 2);
      #pragma unroll
      for (int e = 0; e < EE; ++e) {
        f32x4 gv = *(const f32x4*)(sm.g.gLds + e * DD + d0);   // ds_read_b128
        acc[e] += (double)xv[q].x * gv.x;
        acc[e] += (double)xv[q].y * gv.y;
        acc[e] += (double)xv[q].z * gv.z;
        acc[e] += (double)xv[q].w * gv.w;
      }
    }
    #pragma unroll
    for (int e = 0; e < EE; ++e) {
      #pragma unroll
      for (int off = 32; off > 0; off >>= 1) acc[e] += __shfl_xor(acc[e], off);
    }
    if (lane == 0) {
      float v[EE];
      float m = -1e30f;
      #pragma unroll
      for (int e = 0; e < EE; ++e) { v[e] = (float)acc[e] + gb[e]; m = fmaxf(m, v[e]); }
      float s = 0.f, p[EE];
      #pragma unroll
      for (int e = 0; e < EE; ++e) { p[e] = expf(v[e] - m); s += p[e]; }
      float inv = 1.f / s;
      #pragma unroll
      for (int e = 0; e < EE; ++e) atomicAdd(&sm.g.s_imp[e], p[e] * inv);
      // top-2 (strict > keeps lowest index on ties, matching lax.top_k)
      int i0 = 0; float b0 = v[0];
      #pragma unroll
      for (int e = 1; e < EE; ++e) if (v[e] > b0) { b0 = v[e]; i0 = e; }
      int i1 = -1; float b1v = -1e30f;
      #pragma unroll
      for (int e = 0; e < EE; ++e) if (e != i0 && v[e] > b1v) { b1v = v[e]; i1 = e; }
      float tt = expf(b1v - b0);
      float g0 = 1.f / (1.f + tt), g1 = tt / (1.f + tt);
      int ga = i0 * 2, gbq = i1 * 2 + 1;
      u32 p0 = atomicAdd(&sm.g.s_hist[ga], 1u);
      sm.g.s_lb[ga][p0] = b; sm.g.s_lg[ga][p0] = g0;
      u32 p1 = atomicAdd(&sm.g.s_hist[gbq], 1u);
      sm.g.s_lb[gbq][p1] = b; sm.g.s_lg[gbq][p1] = g1;
    }
    __syncthreads();
    if (tid < NG) sm.g.s_base[tid] = atomicAdd(&cnt[tid * CSTRIDE], sm.g.s_hist[tid]);
    if (tid < EE) atomicAdd(&imp[tid * CSTRIDE], sm.g.s_imp[tid]);
    __syncthreads();
    if (tid < NG * 32) {
      int g = tid >> 5, k = tid & 31;
      if ((u32)k < sm.g.s_hist[g]) {
        u32 pos = sm.g.s_base[g] + (u32)k;
        ridx[g * BB + pos] = sm.g.s_lb[g][k];
        rgate[g * BB + pos] = sm.g.s_lg[g][k];
      }
    }
  } else {
    // ---------------- prep role ----------------
    // (a) stream 16 rows of x -> xb: one row per wave, 4 column-quarters
    {
      int pb = bid - 512;                       // 0..511
      int r = (pb << 4) + (tid >> 6);           // rows r0..r0+15 (in-bounds)
      int ce = (tid & 63) << 2;                 // 64 lanes x 4 elems = 256
      const float* srow = x + (size_t)r * DD;
      bf16_t* drow = xb + (size_t)r * DD;
      #pragma unroll
      for (int q = 0; q < 4; ++q) {
        int d0 = (q << 8) + ce;
        f32x4 v = *(const f32x4*)(srow + d0);
        bf16_t c[4] = {(bf16_t)v.x, (bf16_t)v.y, (bf16_t)v.z, (bf16_t)v.w};
        *(uint2*)(drow + d0) = *(const uint2*)c;
      }
    }
    // (b) 4 x 64x64 W-transpose tiles per block
    int sub = tid >> 8;                 // 0..3
    int t   = tid & 255;
    int pbid = ((bid - 512) << 2) | sub;  // 0..2047
    const float* src; bf16_t* dst; int R, C; int tile;
    if (pbid < 1024) {
      int e = pbid >> 7; tile = pbid & 127;
      src = W1 + (size_t)e * DD * HH; dst = W1T + (size_t)e * HH * DD;
      R = DD; C = HH;
    } else {
      pbid -= 1024;
      int e = pbid >> 7; tile = pbid & 127;
      src = W2 + (size_t)e * HH * OO; dst = W2T + (size_t)e * OO * HH;
      R = HH; C = OO;
    }
    int tpc = C >> 6;
    int r0 = (tile / tpc) << 6, c0 = (tile % tpc) << 6;
    {
      int r = t >> 2, cs = (t & 3) << 4;
      const f32x4* sp = (const f32x4*)(src + (size_t)(r0 + r) * C + c0 + cs);
      #pragma unroll
      for (int q = 0; q < 4; ++q) {
        f32x4 v = sp[q];
        sm.t[sub][cs + q*4 + 0][r] = (bf16_t)v.x;
        sm.t[sub][cs + q*4 + 1][r] = (bf16_t)v.y;
        sm.t[sub][cs + q*4 + 2][r] = (bf16_t)v.z;
        sm.t[sub][cs + q*4 + 3][r] = (bf16_t)v.w;
      }
    }
    __syncthreads();
    {
      int c = t >> 2, rs = (t & 3) << 4;
      bf16_t* op = dst + (size_t)(c0 + c) * R + r0 + rs;
      const uint4* lp = (const uint4*)(&sm.t[sub][c][rs]);
      uint4 a0 = lp[0], a1 = lp[1];
      ((uint4*)op)[0] = a0;
      ((uint4*)op)[1] = a1;
    }
  }
}

// ---------------------------------------------------------------------------
// k_mlp1: grouped GEMM  H[slot][h] = relu(x[row(slot)] @ W1[e] + b1[e])
// 128x64 tile, BK=64, 4 waves, single-buffer 24KB LDS -> 4 blocks/CU.
// Expert->XCD affinity (e = bid&7). Block 0 computes the loss.
// T2 swizzle via pre-swizzled global source + XOR'd ds_read (rule #21).
// ---------------------------------------------------------------------------
__global__ __launch_bounds__(256, 4) void k_mlp1(const u32* __restrict__ cnt,
                                                 const float* __restrict__ imp,
                                                 const int* __restrict__ ridx,
                                                 const bf16_t* __restrict__ xb,
                                                 const bf16_t* __restrict__ W1T,
                                                 const float* __restrict__ b1,
                                                 bf16_t* __restrict__ Hc,
                                                 float* __restrict__ out) {
  __shared__ __align__(16) bf16_t sA[128 * 64];   // 16KB
  __shared__ __align__(16) bf16_t sB[64 * 64];    // 8KB
  __shared__ int s_rb[128];
  __shared__ int s_hb;

  int bid = blockIdx.x;
  int tid = threadIdx.x;

  // load-balance loss (block 0 only, before any early return)
  if (bid == 0 && tid < 64) {
    float v = (tid < EE) ? imp[tid * CSTRIDE] * (1.f / BB) : 0.f;
    v = v * v;
    #pragma unroll
    for (int off = 32; off > 0; off >>= 1) v += __shfl_xor(v, off);
    if (tid == 0) out[(size_t)BB * OO] = 0.01f * (float)EE * v;
  }

  int e = bid & 7;
  int widx = bid >> 3;
  int nt = widx & 7;
  int mt = (widx >> 3) & 63;
  int which = (widx >> 9) & 1;
  int g = e * 2 + which;
  int n = (int)cnt[g * CSTRIDE];
  int m0 = mt << 7;
  if (m0 >= n) return;
  if (tid == 0) {
    int hb = 0;
    for (int g2 = 0; g2 < g; ++g2)
      hb += (((int)cnt[g2 * CSTRIDE] + 127) >> 7) << 7;
    s_hb = hb;
  }
  if (tid < 128) {
    int i = m0 + tid;
    s_rb[tid] = ridx[g * BB + min(i, n - 1)];
  }
  __syncthreads();

  int lane = tid & 63, w = tid >> 6;
  int lrow = lane >> 3;
  // pre-swizzled source column (content of block (lane&7)^(row&7))
  int lcol = (((lane & 7) ^ lrow) << 3);
  int n0 = nt << 6;
  const bf16_t* w1b = W1T + (size_t)e * HH * DD + (size_t)n0 * DD;

  const bf16_t* aptr[4]; const bf16_t* bptr[2];
  #pragma unroll
  for (int q = 0; q < 4; ++q) {
    int r = w * 32 + q * 8 + lrow;
    aptr[q] = xb + (size_t)s_rb[r] * DD + lcol;
  }
  #pragma unroll
  for (int q = 0; q < 2; ++q) {
    int r = w * 16 + q * 8 + lrow;
    bptr[q] = w1b + (size_t)r * DD + lcol;
  }

  f32x4 acc[4][2];
  f32x4 zz = {0.f, 0.f, 0.f, 0.f};
  #pragma unroll
  for (int mm = 0; mm < 4; ++mm)
    #pragma unroll
    for (int nn = 0; nn < 2; ++nn) acc[mm][nn] = zz;

  int lr = lane & 15, lk = lane >> 4;
  int wr = w >> 1, wc = w & 1;
  int rsw = lr & 7;

  for (int kk = 0; kk < 16; ++kk) {
    #pragma unroll
    for (int q = 0; q < 4; ++q) {
      GL16(aptr[q], sA + (w * 32 + q * 8) * 64);
      aptr[q] += 64;
    }
    #pragma unroll
    for (int q = 0; q < 2; ++q) {
      GL16(bptr[q], sB + (w * 16 + q * 8) * 64);
      bptr[q] += 64;
    }
    __syncthreads();
    #pragma unroll
    for (int ks = 0; ks < 2; ++ks) {
      int swb = ((ks * 4 + lk) ^ rsw) << 3;
      bf16x8 af[4], bfr[2];
      #pragma unroll
      for (int mm = 0; mm < 4; ++mm)
        af[mm] = *(const bf16x8*)(sA + (wr * 64 + mm * 16 + lr) * 64 + swb);
      #pragma unroll
      for (int nn = 0; nn < 2; ++nn)
        bfr[nn] = *(const bf16x8*)(sB + (wc * 32 + nn * 16 + lr) * 64 + swb);
      #pragma unroll
      for (int mm = 0; mm < 4; ++mm)
        #pragma unroll
        for (int nn = 0; nn < 2; ++nn)
          acc[mm][nn] = __builtin_amdgcn_mfma_f32_16x16x32_bf16(bfr[nn], af[mm], acc[mm][nn], 0, 0, 0);
    }
    __syncthreads();
  }

  // epilogue: m = wr*64+mm*16+lr ; h-local = wc*32+nn*16+lk*4+j
  int hbase = s_hb + m0;
  const float* b1p = b1 + (size_t)e * HH + n0;
  #pragma unroll
  for (int mm = 0; mm < 4; ++mm) {
    int m = wr * 64 + mm * 16 + lr;
    size_t hrow = (size_t)(hbase + m) * HH + n0;
    #pragma unroll
    for (int nn = 0; nn < 2; ++nn) {
      int h0l = wc * 32 + nn * 16 + lk * 4;
      bf16_t pk[4];
      #pragma unroll
      for (int j = 0; j < 4; ++j)
        pk[j] = (bf16_t)fmaxf(acc[mm][nn][j] + b1p[h0l + j], 0.f);
      *(uint2*)(Hc + hrow + h0l) = *(const uint2*)pk;
    }
  }
}

// ---------------------------------------------------------------------------
// k_mlp2<ADD>: grouped GEMM over group (e*2+ADD); 128x128 tile, single-buffer
// 32.5KB LDS -> 4 blocks/CU, ~1024 active blocks/pass. e = bid&7 affinity.
//   ADD=0: out[row] = g*(H@W2+b2) plain stores (full coverage, no memset)
//   ADD=1: out[row] += ...        non-atomic RMW, stream-ordered after pass A
// ---------------------------------------------------------------------------
template <int ADD>
__global__ __launch_bounds__(256, 4) void k_mlp2(const u32* __restrict__ cnt,
                                                 const int* __restrict__ ridx,
                                                 const float* __restrict__ rgate,
                                                 const bf16_t* __restrict__ Hc,
                                                 const bf16_t* __restrict__ W2T,
                                                 const float* __restrict__ b2,
                                                 float* __restrict__ out) {
  __shared__ __align__(16) bf16_t sA[128 * 64];   // 16KB (H rows)
  __shared__ __align__(16) bf16_t sB[128 * 64];   // 16KB (W2T rows)
  __shared__ int s_rb[128];
  __shared__ float s_rg[128];
  __shared__ int s_hb;

  int bid = blockIdx.x;
  int e = bid & 7; int g = (e << 1) | ADD;
  int t2 = bid >> 3; int nt = t2 & 7; int mt = t2 >> 3;   // mt 0..63
  int n = (int)cnt[g * CSTRIDE];
  int m0 = mt << 7;
  if (m0 >= n) return;
  int tid = threadIdx.x;
  if (tid == 0) {
    int hb = 0;
    for (int g2 = 0; g2 < g; ++g2)
      hb += (((int)cnt[g2 * CSTRIDE] + 127) >> 7) << 7;
    s_hb = hb;
  }
  if (tid < 128) {
    int i = m0 + tid;
    int ic = min(i, n - 1);
    s_rb[tid] = ridx[g * BB + ic];
    s_rg[tid] = (i < n) ? rgate[g * BB + ic] : 0.f;
  }
  __syncthreads();

  int lane = tid & 63, w = tid >> 6;
  int lrow = lane >> 3;
  int lcol = (((lane & 7) ^ lrow) << 3);
  int n0 = nt << 7;
  int hbase = s_hb + m0;
  const bf16_t* w2b = W2T + (size_t)e * OO * HH + (size_t)n0 * HH;

  const bf16_t* aptr[4]; const bf16_t* bptr[4];
  #pragma unroll
  for (int q = 0; q < 4; ++q) {
    int r = w * 32 + q * 8 + lrow;
    aptr[q] = Hc + (size_t)(hbase + r) * HH + lcol;
    bptr[q] = w2b + (size_t)r * HH + lcol;
  }

  f32x4 acc[4][4];
  f32x4 zz = {0.f, 0.f, 0.f, 0.f};
  #pragma unroll
  for (int mm = 0; mm < 4; ++mm)
    #pragma unroll
    for (int nn = 0; nn < 4; ++nn) acc[mm][nn] = zz;

  int lr = lane & 15, lk = lane >> 4;
  int wr = w >> 1, wc = w & 1;
  int rsw = lr & 7;

  for (int kk = 0; kk < 8; ++kk) {
    #pragma unroll
    for (int q = 0; q < 4; ++q) {
      GL16(aptr[q], sA + (w * 32 + q * 8) * 64);
      GL16(bptr[q], sB + (w * 32 + q * 8) * 64);
      aptr[q] += 64; bptr[q] += 64;
    }
    __syncthreads();
    #pragma unroll
    for (int ks = 0; ks < 2; ++ks) {
      int swb = ((ks * 4 + lk) ^ rsw) << 3;
      bf16x8 af[4], bfr[4];
      #pragma unroll
      for (int mm = 0; mm < 4; ++mm)
        af[mm] = *(const bf16x8*)(sA + (wr * 64 + mm * 16 + lr) * 64 + swb);
      #pragma unroll
      for (int nn = 0; nn < 4; ++nn)
        bfr[nn] = *(const bf16x8*)(sB + (wc * 64 + nn * 16 + lr) * 64 + swb);
      #pragma unroll
      for (int mm = 0; mm < 4; ++mm)
        #pragma unroll
        for (int nn = 0; nn < 4; ++nn)
          acc[mm][nn] = __builtin_amdgcn_mfma_f32_16x16x32_bf16(bfr[nn], af[mm], acc[mm][nn], 0, 0, 0);
    }
    __syncthreads();
  }

  // epilogue: m = wr*64+mm*16+lr ; o-local = wc*64+nn*16+lk*4+j
  const float* b2p = b2 + (size_t)e * OO + n0;
  #pragma unroll
  for (int mm = 0; mm < 4; ++mm) {
    int m = wr * 64 + mm * 16 + lr;
    if (m0 + m < n) {
      float gg = s_rg[m];
      float* orow = out + (size_t)s_rb[m] * OO + n0;
      #pragma unroll
      for (int nn = 0; nn < 4; ++nn) {
        int o0 = wc * 64 + nn * 16 + lk * 4;
        f32x4 v;
        #pragma unroll
        for (int j = 0; j < 4; ++j)
          v[j] = (acc[mm][nn][j] + b2p[o0 + j]) * gg;
        if (ADD) {
          f32x4 old = *(const f32x4*)(orow + o0);
          v += old;
        }
        *(f32x4*)(orow + o0) = v;
      }
    }
  }
}

// ---------------------------------------------------------------------------
extern "C" void kernel_launch(void* const* d_in, const int* in_sizes, int n_in,
                              void* d_out, int out_size, void* d_ws, size_t ws_size,
                              hipStream_t stream) {
  const float* x   = (const float*)d_in[0];
  const float* gW  = (const float*)d_in[1];
  const float* gb  = (const float*)d_in[2];
  const float* W1  = (const float*)d_in[3];
  const float* b1  = (const float*)d_in[4];
  const float* W2  = (const float*)d_in[5];
  const float* b2  = (const float*)d_in[6];
  float* out = (float*)d_out;

  uint8_t* ws = (uint8_t*)d_ws;
  float*   imp   = (float*)(ws + 0);
  u32*     cnt   = (u32*)(ws + WS_CNT);
  int*     ridx  = (int*)(ws + WS_RIDX);
  float*   rgate = (float*)(ws + WS_RGATE);
  bf16_t*  xb    = (bf16_t*)(ws + WS_XB);
  bf16_t*  W1T   = (bf16_t*)(ws + WS_W1T);
  bf16_t*  W2T   = (bf16_t*)(ws + WS_W2T);
  bf16_t*  Hc    = (bf16_t*)(ws + WS_H);

  // zero counters/importance only (out fully overwritten by mlp2<0> + loss)
  hipMemsetAsync(ws, 0, 2048, stream);

  k_pg<<<1024, 1024, 0, stream>>>(x, gW, gb, W1, W2, imp, cnt, ridx, rgate,
                                  xb, W1T, W2T);
  k_mlp1<<<8192, 256, 0, stream>>>(cnt, imp, ridx, xb, W1T, b1, Hc, out);
  k_mlp2<0><<<4096, 256, 0, stream>>>(cnt, ridx, rgate, Hc, W2T, b2, out);
  k_mlp2<1><<<4096, 256, 0, stream>>>(cnt, ridx, rgate, Hc, W2T, b2, out);
}

// Round 18
// 120.816 us; speedup vs baseline: 1.0328x; 1.0328x over previous
//
#include <hip/hip_runtime.h>
#include <hip/hip_bf16.h>
#include <stdint.h>

// Problem constants
#define BB 8192
#define DD 1024
#define EE 8
#define HH 512
#define OO 1024
#define NG 16   // groups = expert*2 + which (0=primary,1=secondary)

typedef __bf16 bf16_t;
typedef bf16_t bf16x8 __attribute__((ext_vector_type(8)));
typedef float f32x4 __attribute__((ext_vector_type(4)));
typedef uint32_t u32;

// Padded counter stride: 64B per counter -> no cache-line sharing
#define CSTRIDE 16

// ---------------- ws layout (bytes) ----------------
#define WS_CNT    1024                                    // u32[16] stride 16
#define WS_RIDX   4096                                    // int[16][8192]  (512KB)
#define WS_RGATE  (4096 + NG*BB*4)                        // f32[16][8192]  (512KB)
#define WS_XB     (2u<<20)                                // bf16[8192][1024]
#define WS_W1T    (WS_XB + (size_t)BB*DD*2)               // bf16[8][512][1024]
#define WS_W2T    (WS_W1T + (size_t)EE*HH*DD*2)           // bf16[8][1024][512]
#define WS_H      (WS_W2T + (size_t)EE*OO*HH*2)           // bf16[18432][512]
// total ~54.5 MB

// async global->LDS, 16B per lane, LDS dest = wave-uniform base + lane*16
#define GL16(gsrc, ldst)                                                       \
  __builtin_amdgcn_global_load_lds(                                            \
      (const __attribute__((address_space(1))) void*)(gsrc),                   \
      (__attribute__((address_space(3))) void*)(ldst), 16, 0, 0)

// ---------------------------------------------------------------------------
// Co-launched prep + gate (round-12 configuration — session best, 121.1 µs).
// Blocks [0,512): gate — 16 waves, 1 row/wave, xb emission inline.
// Blocks [512,1024): prep — 4 x 64x64 W-transpose tiles per block.
// k_pg ledger: r13 in-wave ILP -> scratch spill; r14 2-wave split -> 2x
// staging; r15 load-hoist -> null; r17 xb-offload -> -3 µs. Keep r12.
// ---------------------------------------------------------------------------
union __align__(16) PGSmem {
  struct {
    float gLds[EE * DD];            // 32KB, [e][d]
    float s_imp[EE];
    u32   s_hist[NG];
    u32   s_base[NG];
    int   s_lb[NG][32];
    float s_lg[NG][32];
  } g;
  bf16_t t[4][64][72];              // 36.9KB (+8 pad -> 144B row stride)
};

__global__ __launch_bounds__(1024, 8) void k_pg(const float* __restrict__ x,
                                                const float* __restrict__ gW,
                                                const float* __restrict__ gb,
                                                const float* __restrict__ W1,
                                                const float* __restrict__ W2,
                                                float* __restrict__ imp,
                                                u32* __restrict__ cnt,
                                                int* __restrict__ ridx,
                                                float* __restrict__ rgate,
                                                bf16_t* __restrict__ xb,
                                                bf16_t* __restrict__ W1T,
                                                bf16_t* __restrict__ W2T) {
  __shared__ PGSmem sm;
  int tid = threadIdx.x;
  int bid = blockIdx.x;

  if (bid < 512) {
    // ---------------- gate role ----------------
    if (tid < EE) sm.g.s_imp[tid] = 0.f;
    if (tid < NG) sm.g.s_hist[tid] = 0u;
    {
      const f32x4* gp = (const f32x4*)(gW + (size_t)tid * EE);
      f32x4 g0 = gp[0], g1 = gp[1];
      sm.g.gLds[0 * DD + tid] = g0.x; sm.g.gLds[1 * DD + tid] = g0.y;
      sm.g.gLds[2 * DD + tid] = g0.z; sm.g.gLds[3 * DD + tid] = g0.w;
      sm.g.gLds[4 * DD + tid] = g1.x; sm.g.gLds[5 * DD + tid] = g1.y;
      sm.g.gLds[6 * DD + tid] = g1.z; sm.g.gLds[7 * DD + tid] = g1.w;
    }
    __syncthreads();

    int lane = tid & 63, w = tid >> 6;
    int b = (bid << 4) + w;
    const float* xrow = x + (size_t)b * DD;
    bf16_t* xbrow = xb + (size_t)b * DD;

    double acc[EE];
    #pragma unroll
    for (int e = 0; e < EE; ++e) acc[e] = 0.0;

    #pragma unroll
    for (int q = 0; q < 4; ++q) {
      int d0 = (q << 8) + (lane << 2);
      f32x4 xv = *(const f32x4*)(xrow + d0);
      bf16_t xc[4] = {(bf16_t)xv.x, (bf16_t)xv.y, (bf16_t)xv.z, (bf16_t)xv.w};
      *(uint2*)(xbrow + d0) = *(const uint2*)xc;
      #pragma unroll
      for (int e = 0; e < EE; ++e) {
        f32x4 gv = *(const f32x4*)(sm.g.gLds + e * DD + d0);   // ds_read_b128
        acc[e] += (double)xv.x * gv.x;
        acc[e] += (double)xv.y * gv.y;
        acc[e] += (double)xv.z * gv.z;
        acc[e] += (double)xv.w * gv.w;
      }
    }
    #pragma unroll
    for (int e = 0; e < EE; ++e) {
      #pragma unroll
      for (int off = 32; off > 0; off >>= 1) acc[e] += __shfl_xor(acc[e], off);
    }
    if (lane == 0) {
      float v[EE];
      float m = -1e30f;
      #pragma unroll
      for (int e = 0; e < EE; ++e) { v[e] = (float)acc[e] + gb[e]; m = fmaxf(m, v[e]); }
      float s = 0.f, p[EE];
      #pragma unroll
      for (int e = 0; e < EE; ++e) { p[e] = expf(v[e] - m); s += p[e]; }
      float inv = 1.f / s;
      #pragma unroll
      for (int e = 0; e < EE; ++e) atomicAdd(&sm.g.s_imp[e], p[e] * inv);
      // top-2 (strict > keeps lowest index on ties, matching lax.top_k)
      int i0 = 0; float b0 = v[0];
      #pragma unroll
      for (int e = 1; e < EE; ++e) if (v[e] > b0) { b0 = v[e]; i0 = e; }
      int i1 = -1; float b1v = -1e30f;
      #pragma unroll
      for (int e = 0; e < EE; ++e) if (e != i0 && v[e] > b1v) { b1v = v[e]; i1 = e; }
      float tt = expf(b1v - b0);
      float g0 = 1.f / (1.f + tt), g1 = tt / (1.f + tt);
      int ga = i0 * 2, gbq = i1 * 2 + 1;
      u32 p0 = atomicAdd(&sm.g.s_hist[ga], 1u);
      sm.g.s_lb[ga][p0] = b; sm.g.s_lg[ga][p0] = g0;
      u32 p1 = atomicAdd(&sm.g.s_hist[gbq], 1u);
      sm.g.s_lb[gbq][p1] = b; sm.g.s_lg[gbq][p1] = g1;
    }
    __syncthreads();
    if (tid < NG) sm.g.s_base[tid] = atomicAdd(&cnt[tid * CSTRIDE], sm.g.s_hist[tid]);
    if (tid < EE) atomicAdd(&imp[tid * CSTRIDE], sm.g.s_imp[tid]);
    __syncthreads();
    if (tid < NG * 32) {
      int g = tid >> 5, k = tid & 31;
      if ((u32)k < sm.g.s_hist[g]) {
        u32 pos = sm.g.s_base[g] + (u32)k;
        ridx[g * BB + pos] = sm.g.s_lb[g][k];
        rgate[g * BB + pos] = sm.g.s_lg[g][k];
      }
    }
  } else {
    // ---------------- prep role: 4 x 64x64 tiles per block ----------------
    int sub = tid >> 8;                 // 0..3
    int t   = tid & 255;
    int pbid = ((bid - 512) << 2) | sub;  // 0..2047
    const float* src; bf16_t* dst; int R, C; int tile;
    if (pbid < 1024) {
      int e = pbid >> 7; tile = pbid & 127;
      src = W1 + (size_t)e * DD * HH; dst = W1T + (size_t)e * HH * DD;
      R = DD; C = HH;
    } else {
      pbid -= 1024;
      int e = pbid >> 7; tile = pbid & 127;
      src = W2 + (size_t)e * HH * OO; dst = W2T + (size_t)e * OO * HH;
      R = HH; C = OO;
    }
    int tpc = C >> 6;
    int r0 = (tile / tpc) << 6, c0 = (tile % tpc) << 6;
    {
      int r = t >> 2, cs = (t & 3) << 4;
      const f32x4* sp = (const f32x4*)(src + (size_t)(r0 + r) * C + c0 + cs);
      #pragma unroll
      for (int q = 0; q < 4; ++q) {
        f32x4 v = sp[q];
        sm.t[sub][cs + q*4 + 0][r] = (bf16_t)v.x;
        sm.t[sub][cs + q*4 + 1][r] = (bf16_t)v.y;
        sm.t[sub][cs + q*4 + 2][r] = (bf16_t)v.z;
        sm.t[sub][cs + q*4 + 3][r] = (bf16_t)v.w;
      }
    }
    __syncthreads();
    {
      int c = t >> 2, rs = (t & 3) << 4;
      bf16_t* op = dst + (size_t)(c0 + c) * R + r0 + rs;
      const uint4* lp = (const uint4*)(&sm.t[sub][c][rs]);
      uint4 a0 = lp[0], a1 = lp[1];
      ((uint4*)op)[0] = a0;
      ((uint4*)op)[1] = a1;
    }
  }
}

// ---------------------------------------------------------------------------
// k_mlp1: grouped GEMM  H[slot][h] = relu(x[row(slot)] @ W1[e] + b1[e])
// 128x64 tile, BK=64, 4 waves, single-buffer 24KB LDS -> 4 blocks/CU.
// Expert->XCD affinity (e = bid&7). Block 0 computes the loss.
// T2 swizzle via pre-swizzled global source + XOR'd ds_read (rule #21).
// ---------------------------------------------------------------------------
__global__ __launch_bounds__(256, 4) void k_mlp1(const u32* __restrict__ cnt,
                                                 const float* __restrict__ imp,
                                                 const int* __restrict__ ridx,
                                                 const bf16_t* __restrict__ xb,
                                                 const bf16_t* __restrict__ W1T,
                                                 const float* __restrict__ b1,
                                                 bf16_t* __restrict__ Hc,
                                                 float* __restrict__ out) {
  __shared__ __align__(16) bf16_t sA[128 * 64];   // 16KB
  __shared__ __align__(16) bf16_t sB[64 * 64];    // 8KB
  __shared__ int s_rb[128];
  __shared__ int s_hb;

  int bid = blockIdx.x;
  int tid = threadIdx.x;

  // load-balance loss (block 0 only, before any early return)
  if (bid == 0 && tid < 64) {
    float v = (tid < EE) ? imp[tid * CSTRIDE] * (1.f / BB) : 0.f;
    v = v * v;
    #pragma unroll
    for (int off = 32; off > 0; off >>= 1) v += __shfl_xor(v, off);
    if (tid == 0) out[(size_t)BB * OO] = 0.01f * (float)EE * v;
  }

  int e = bid & 7;
  int widx = bid >> 3;
  int nt = widx & 7;
  int mt = (widx >> 3) & 63;
  int which = (widx >> 9) & 1;
  int g = e * 2 + which;
  int n = (int)cnt[g * CSTRIDE];
  int m0 = mt << 7;
  if (m0 >= n) return;
  if (tid == 0) {
    int hb = 0;
    for (int g2 = 0; g2 < g; ++g2)
      hb += (((int)cnt[g2 * CSTRIDE] + 127) >> 7) << 7;
    s_hb = hb;
  }
  if (tid < 128) {
    int i = m0 + tid;
    s_rb[tid] = ridx[g * BB + min(i, n - 1)];
  }
  __syncthreads();

  int lane = tid & 63, w = tid >> 6;
  int lrow = lane >> 3;
  // pre-swizzled source column (content of block (lane&7)^(row&7))
  int lcol = (((lane & 7) ^ lrow) << 3);
  int n0 = nt << 6;
  const bf16_t* w1b = W1T + (size_t)e * HH * DD + (size_t)n0 * DD;

  const bf16_t* aptr[4]; const bf16_t* bptr[2];
  #pragma unroll
  for (int q = 0; q < 4; ++q) {
    int r = w * 32 + q * 8 + lrow;
    aptr[q] = xb + (size_t)s_rb[r] * DD + lcol;
  }
  #pragma unroll
  for (int q = 0; q < 2; ++q) {
    int r = w * 16 + q * 8 + lrow;
    bptr[q] = w1b + (size_t)r * DD + lcol;
  }

  f32x4 acc[4][2];
  f32x4 zz = {0.f, 0.f, 0.f, 0.f};
  #pragma unroll
  for (int mm = 0; mm < 4; ++mm)
    #pragma unroll
    for (int nn = 0; nn < 2; ++nn) acc[mm][nn] = zz;

  int lr = lane & 15, lk = lane >> 4;
  int wr = w >> 1, wc = w & 1;
  int rsw = lr & 7;

  for (int kk = 0; kk < 16; ++kk) {
    #pragma unroll
    for (int q = 0; q < 4; ++q) {
      GL16(aptr[q], sA + (w * 32 + q * 8) * 64);
      aptr[q] += 64;
    }
    #pragma unroll
    for (int q = 0; q < 2; ++q) {
      GL16(bptr[q], sB + (w * 16 + q * 8) * 64);
      bptr[q] += 64;
    }
    __syncthreads();
    #pragma unroll
    for (int ks = 0; ks < 2; ++ks) {
      int swb = ((ks * 4 + lk) ^ rsw) << 3;
      bf16x8 af[4], bfr[2];
      #pragma unroll
      for (int mm = 0; mm < 4; ++mm)
        af[mm] = *(const bf16x8*)(sA + (wr * 64 + mm * 16 + lr) * 64 + swb);
      #pragma unroll
      for (int nn = 0; nn < 2; ++nn)
        bfr[nn] = *(const bf16x8*)(sB + (wc * 32 + nn * 16 + lr) * 64 + swb);
      #pragma unroll
      for (int mm = 0; mm < 4; ++mm)
        #pragma unroll
        for (int nn = 0; nn < 2; ++nn)
          acc[mm][nn] = __builtin_amdgcn_mfma_f32_16x16x32_bf16(bfr[nn], af[mm], acc[mm][nn], 0, 0, 0);
    }
    __syncthreads();
  }

  // epilogue: m = wr*64+mm*16+lr ; h-local = wc*32+nn*16+lk*4+j
  int hbase = s_hb + m0;
  const float* b1p = b1 + (size_t)e * HH + n0;
  #pragma unroll
  for (int mm = 0; mm < 4; ++mm) {
    int m = wr * 64 + mm * 16 + lr;
    size_t hrow = (size_t)(hbase + m) * HH + n0;
    #pragma unroll
    for (int nn = 0; nn < 2; ++nn) {
      int h0l = wc * 32 + nn * 16 + lk * 4;
      bf16_t pk[4];
      #pragma unroll
      for (int j = 0; j < 4; ++j)
        pk[j] = (bf16_t)fmaxf(acc[mm][nn][j] + b1p[h0l + j], 0.f);
      *(uint2*)(Hc + hrow + h0l) = *(const uint2*)pk;
    }
  }
}

// ---------------------------------------------------------------------------
// k_mlp2<ADD>: grouped GEMM over group (e*2+ADD); 128x128 tile, single-buffer
// 32.5KB LDS -> 4 blocks/CU, ~1024 active blocks/pass. e = bid&7 affinity.
//   ADD=0: out[row] = g*(H@W2+b2) plain stores (full coverage, no memset)
//   ADD=1: out[row] += ...        non-atomic RMW, stream-ordered after pass A
// ---------------------------------------------------------------------------
template <int ADD>
__global__ __launch_bounds__(256, 4) void k_mlp2(const u32* __restrict__ cnt,
                                                 const int* __restrict__ ridx,
                                                 const float* __restrict__ rgate,
                                                 const bf16_t* __restrict__ Hc,
                                                 const bf16_t* __restrict__ W2T,
                                                 const float* __restrict__ b2,
                                                 float* __restrict__ out) {
  __shared__ __align__(16) bf16_t sA[128 * 64];   // 16KB (H rows)
  __shared__ __align__(16) bf16_t sB[128 * 64];   // 16KB (W2T rows)
  __shared__ int s_rb[128];
  __shared__ float s_rg[128];
  __shared__ int s_hb;

  int bid = blockIdx.x;
  int e = bid & 7; int g = (e << 1) | ADD;
  int t2 = bid >> 3; int nt = t2 & 7; int mt = t2 >> 3;   // mt 0..63
  int n = (int)cnt[g * CSTRIDE];
  int m0 = mt << 7;
  if (m0 >= n) return;
  int tid = threadIdx.x;
  if (tid == 0) {
    int hb = 0;
    for (int g2 = 0; g2 < g; ++g2)
      hb += (((int)cnt[g2 * CSTRIDE] + 127) >> 7) << 7;
    s_hb = hb;
  }
  if (tid < 128) {
    int i = m0 + tid;
    int ic = min(i, n - 1);
    s_rb[tid] = ridx[g * BB + ic];
    s_rg[tid] = (i < n) ? rgate[g * BB + ic] : 0.f;
  }
  __syncthreads();

  int lane = tid & 63, w = tid >> 6;
  int lrow = lane >> 3;
  int lcol = (((lane & 7) ^ lrow) << 3);
  int n0 = nt << 7;
  int hbase = s_hb + m0;
  const bf16_t* w2b = W2T + (size_t)e * OO * HH + (size_t)n0 * HH;

  const bf16_t* aptr[4]; const bf16_t* bptr[4];
  #pragma unroll
  for (int q = 0; q < 4; ++q) {
    int r = w * 32 + q * 8 + lrow;
    aptr[q] = Hc + (size_t)(hbase + r) * HH + lcol;
    bptr[q] = w2b + (size_t)r * HH + lcol;
  }

  f32x4 acc[4][4];
  f32x4 zz = {0.f, 0.f, 0.f, 0.f};
  #pragma unroll
  for (int mm = 0; mm < 4; ++mm)
    #pragma unroll
    for (int nn = 0; nn < 4; ++nn) acc[mm][nn] = zz;

  int lr = lane & 15, lk = lane >> 4;
  int wr = w >> 1, wc = w & 1;
  int rsw = lr & 7;

  for (int kk = 0; kk < 8; ++kk) {
    #pragma unroll
    for (int q = 0; q < 4; ++q) {
      GL16(aptr[q], sA + (w * 32 + q * 8) * 64);
      GL16(bptr[q], sB + (w * 32 + q * 8) * 64);
      aptr[q] += 64; bptr[q] += 64;
    }
    __syncthreads();
    #pragma unroll
    for (int ks = 0; ks < 2; ++ks) {
      int swb = ((ks * 4 + lk) ^ rsw) << 3;
      bf16x8 af[4], bfr[4];
      #pragma unroll
      for (int mm = 0; mm < 4; ++mm)
        af[mm] = *(const bf16x8*)(sA + (wr * 64 + mm * 16 + lr) * 64 + swb);
      #pragma unroll
      for (int nn = 0; nn < 4; ++nn)
        bfr[nn] = *(const bf16x8*)(sB + (wc * 64 + nn * 16 + lr) * 64 + swb);
      #pragma unroll
      for (int mm = 0; mm < 4; ++mm)
        #pragma unroll
        for (int nn = 0; nn < 4; ++nn)
          acc[mm][nn] = __builtin_amdgcn_mfma_f32_16x16x32_bf16(bfr[nn], af[mm], acc[mm][nn], 0, 0, 0);
    }
    __syncthreads();
  }

  // epilogue: m = wr*64+mm*16+lr ; o-local = wc*64+nn*16+lk*4+j
  const float* b2p = b2 + (size_t)e * OO + n0;
  #pragma unroll
  for (int mm = 0; mm < 4; ++mm) {
    int m = wr * 64 + mm * 16 + lr;
    if (m0 + m < n) {
      float gg = s_rg[m];
      float* orow = out + (size_t)s_rb[m] * OO + n0;
      #pragma unroll
      for (int nn = 0; nn < 4; ++nn) {
        int o0 = wc * 64 + nn * 16 + lk * 4;
        f32x4 v;
        #pragma unroll
        for (int j = 0; j < 4; ++j)
          v[j] = (acc[mm][nn][j] + b2p[o0 + j]) * gg;
        if (ADD) {
          f32x4 old = *(const f32x4*)(orow + o0);
          v += old;
        }
        *(f32x4*)(orow + o0) = v;
      }
    }
  }
}

// ---------------------------------------------------------------------------
extern "C" void kernel_launch(void* const* d_in, const int* in_sizes, int n_in,
                              void* d_out, int out_size, void* d_ws, size_t ws_size,
                              hipStream_t stream) {
  const float* x   = (const float*)d_in[0];
  const float* gW  = (const float*)d_in[1];
  const float* gb  = (const float*)d_in[2];
  const float* W1  = (const float*)d_in[3];
  const float* b1  = (const float*)d_in[4];
  const float* W2  = (const float*)d_in[5];
  const float* b2  = (const float*)d_in[6];
  float* out = (float*)d_out;

  uint8_t* ws = (uint8_t*)d_ws;
  float*   imp   = (float*)(ws + 0);
  u32*     cnt   = (u32*)(ws + WS_CNT);
  int*     ridx  = (int*)(ws + WS_RIDX);
  float*   rgate = (float*)(ws + WS_RGATE);
  bf16_t*  xb    = (bf16_t*)(ws + WS_XB);
  bf16_t*  W1T   = (bf16_t*)(ws + WS_W1T);
  bf16_t*  W2T   = (bf16_t*)(ws + WS_W2T);
  bf16_t*  Hc    = (bf16_t*)(ws + WS_H);

  // zero counters/importance only (out fully overwritten by mlp2<0> + loss)
  hipMemsetAsync(ws, 0, 2048, stream);

  k_pg<<<1024, 1024, 0, stream>>>(x, gW, gb, W1, W2, imp, cnt, ridx, rgate,
                                  xb, W1T, W2T);
  k_mlp1<<<8192, 256, 0, stream>>>(cnt, imp, ridx, xb, W1T, b1, Hc, out);
  k_mlp2<0><<<4096, 256, 0, stream>>>(cnt, ridx, rgate, Hc, W2T, b2, out);
  k_mlp2<1><<<4096, 256, 0, stream>>>(cnt, ridx, rgate, Hc, W2T, b2, out);
}